// Round 8
// baseline (276.513 us; speedup 1.0000x reference)
//
#include <hip/hip_runtime.h>

// Soft differentiable rasterizer, forward only. Two-kernel structure.
// R16 -> R17: same occupancy theory, SAFE implementation. R16's global
// atomic work-queue persistent kernel killed the container twice (hang or
// replay tripwire; rocprof replay without setup re-run would see stale
// g_wq). R17 keeps the theory — Occupancy 45% = block-granularity
// residency trapping (4 waves/block own 4 different tiles; block retires
// with its slowest wave) — but uses a STATIC wave-strided persistent
// schedule: grid = 2048 blocks (8/CU -> full 32 waves/CU residency at
// VGPR 16), 8192 waves x exactly 6 tiles each (t = wid + k*8192, k<6).
// No atomics, no cross-WG state, deterministic, graph/replay-safe.
// Stride interleaves each wave's 6 tiles across frames+regions (variance
// ~1/sqrt(6)); a wave finishing early-exit tile k starts k+1 immediately
// (no sibling-wave wait).
// R15 post-mortem (carried): mask-loop raster 125us; rest ~72us mostly
// harness re-poison of 37.7MB output + setup; raster model per slot-iter
// ~36cy packed VALU + ~96cy trans (12 x wave64 exp2 @ 1/4 rate) ->
// trans-bound, floor ~80us at full feed.
// Design (R8/R9/R15): 32x2 px tiles, per-edge line-form interval cull,
// pos-first packing, 128-bit survivor mask per tile, scalar-mask ff1
// next-slot, packed-fp32 sigmoid product, front-to-back T, exit T<2e-3.

#define HH 128
#define WW 128
#define NN 128
#define KK 12
#define STPB 1024
#define RTPB 256
#define RBLKS 2048                  // 8 blocks/CU x 256 CUs
#define STATE_SZ (NN * KK * 2 + NN) // 3200
#define CULL_U 15.0f
#define COEF_STRIDE 40              // floats per slot: A[12] B[12] C[12] gc[4]
#define PQ_STRIDE 18                // float2 per slot (padded; 36 words)

typedef float f2 __attribute__((ext_vector_type(2)));

__global__ __launch_bounds__(STPB) void setup_kernel(
    const float* __restrict__ traj,
    const float* __restrict__ colors,
    const float* __restrict__ alpha,
    const float* __restrict__ zval,
    const void*  __restrict__ csg_raw,
    float* __restrict__ g_coef,               // [T][128][40]
    unsigned long long* __restrict__ g_mask)  // [T][256][2] 128-bit keep mask
{
    __shared__ __align__(16) float s_coef[NN][COEF_STRIDE];       // 20.5 KB
    __shared__ __align__(16) float2 s_pq[NN][PQ_STRIDE];          // 18 KB
    __shared__ float s_state[STATE_SZ];                           // 12.8 KB
    __shared__ float s_orient[NN];
    __shared__ float s_z[NN];
    __shared__ int   s_slot2prim[NN];
    __shared__ int   s_npos[NN], s_nneg[NN];
    __shared__ unsigned long long s_qbits[HH][4][2];              // 8 KB
    __shared__ int s_mode;

    const int frame = blockIdx.x;
    const int tid   = threadIdx.x;
    const float* st = traj + (size_t)frame * STATE_SZ;

    // ---- stage + csg layout detect (one-wave ballot) + counter init ----
    for (int i = tid; i < STATE_SZ; i += STPB) s_state[i] = st[i];
    if (tid < NN) { s_z[tid] = zval[tid]; s_npos[tid] = 0; s_nneg[tid] = 0; }
    if (tid < 64) {
        unsigned w = (tid < 32) ? ((const unsigned*)csg_raw)[tid] : 0u;
        unsigned long long anyw = __ballot(w > 1u);            // some word not 0/1
        unsigned long long anyb = __ballot((w & 0xFEFEFEFEu) != 0u); // some byte > 1
        if (tid == 0) s_mode = (anyw == 0ull) ? 0 : ((anyb == 0ull) ? 1 : 2);
    }
    __syncthreads();

    // ---- per-prim: orient, g = alpha*sigmoid(alive), z-rank -> slot ----
    if (tid < NN) {
        const int n = tid;
        float area2 = 0.f;
        #pragma unroll
        for (int k = 0; k < KK; k++) {
            int k1 = (k + 1) % KK;
            float v0x = s_state[(n * KK + k)  * 2 + 0];
            float v0y = s_state[(n * KK + k)  * 2 + 1];
            float v1x = s_state[(n * KK + k1) * 2 + 0];
            float v1y = s_state[(n * KK + k1) * 2 + 1];
            area2 += v0x * v1y - v1x * v0y;
        }
        float orient = (area2 > 0.f) ? 1.f : ((area2 < 0.f) ? -1.f : 0.f);
        s_orient[n] = orient;

        float alive = s_state[NN * KK * 2 + n];
        float g = alpha[n] / (1.f + __expf(-alive));

        float zn = s_z[n];
        int rank = 0;
        #pragma unroll 8
        for (int j = 0; j < NN; j++) {
            float zj = s_z[j];
            rank += (zj < zn || (zj == zn && j < n)) ? 1 : 0;
        }
        int slot = (NN - 1) - rank; // slot 0 = frontmost (largest z)
        s_slot2prim[slot] = n;

        int mode = s_mode;
        int sub;
        if (mode == 0)      sub = ((const int*)csg_raw)[n] != 0;
        else if (mode == 1) sub = ((const unsigned char*)csg_raw)[n] != 0;
        else                sub = ((const float*)csg_raw)[n] != 0.f;
        float cs = sub ? 0.f : 1.f;
        s_coef[slot][36] = g;
        s_coef[slot][37] = colors[n * 3 + 0] * cs;
        s_coef[slot][38] = colors[n * 3 + 1] * cs;
        s_coef[slot][39] = colors[n * 3 + 2] * cs;
    }
    __syncthreads();

    // ---- edge coefficients (slot-ordered SoA) ----
    const float QSCALE = 100.0f * 1.4426950408889634f;
    for (int idx = tid; idx < NN * KK; idx += STPB) {
        int slot = idx / KK;
        int k    = idx - slot * KK;
        int n    = s_slot2prim[slot];
        int k1   = (k + 1) % KK;
        float v0x = s_state[(n * KK + k)  * 2 + 0];
        float v0y = s_state[(n * KK + k)  * 2 + 1];
        float v1x = s_state[(n * KK + k1) * 2 + 0];
        float v1y = s_state[(n * KK + k1) * 2 + 1];
        float ex = v1x - v0x, ey = v1y - v0y;
        float q  = -s_orient[n] * QSCALE;
        s_coef[slot][0  + k] = q * ex;                      // A
        s_coef[slot][12 + k] = -q * ey;                     // B
        s_coef[slot][24 + k] = -q * (ex * v0y - ey * v0x);  // C
    }
    __syncthreads();

    // ---- line form per edge: x-constraint t(gy) = Q*gy + P ----
    // B>0: x <= t (+SLACK); B<0: x >= t (stored negated: -x <= -t, +SLACK);
    // B==0: no x-constraint -> neg-bucket entry with t' = +1e30 (never binds).
    // Pos edges packed first (k < npos). STRIDED LOOP (R8 bug: bare if).
    const float SLACK = 0.01f;
    for (int idx = tid; idx < NN * KK; idx += STPB) {
        int slot = idx / KK;
        int k    = idx - slot * KK;
        (void)k;
        float A = s_coef[slot][idx - slot * KK];
        float B = s_coef[slot][12 + (idx - slot * KK)];
        float C = s_coef[slot][24 + (idx - slot * KK)];
        float rcpB = __builtin_amdgcn_rcpf(B);
        float Praw = (CULL_U - C) * rcpB;
        float Qraw = -A * rcpB;
        if (B > 0.f) {
            int i = atomicAdd(&s_npos[slot], 1);
            s_pq[slot][i] = make_float2(Qraw, Praw + SLACK);
        } else if (B < 0.f) {
            int i = atomicAdd(&s_nneg[slot], 1);
            s_pq[slot][(KK - 1) - i] = make_float2(-Qraw, -Praw + SLACK);
        } else { // B == 0: x-independent edge; conservatively no constraint
            int i = atomicAdd(&s_nneg[slot], 1);
            s_pq[slot][(KK - 1) - i] = make_float2(0.f, 1e30f);
        }
    }
    __syncthreads();

    // ---- joint interval cull; 4 x-quarter keep masks per row ----
    // wave covers one row (r const) x 64 slots (s = s0 + lane).
    const float GX_LO = 0.5f / WW;
    const float GX_HI = (WW - 0.5f) / WW;
    for (int j = 0; j < (HH * NN) / STPB; j++) {     // 16 iters
        int idx = j * STPB + tid;
        int r = idx >> 7, s = idx & (NN - 1);
        float gyr = (r + 0.5f) * (1.0f / HH);
        int npos = s_npos[s];
        const float4* pq4 = (const float4*)&s_pq[s][0];
        float y1 = 1e30f, y2 = 1e30f;
        #pragma unroll
        for (int h = 0; h < KK / 2; h++) {
            float4 v = pq4[h];                       // {Q,P,Q,P}
            int k0 = 2 * h, k1 = 2 * h + 1;
            float t0 = fmaf(v.x, gyr, v.y);
            float t1 = fmaf(v.z, gyr, v.w);
            bool p0 = k0 < npos, p1 = k1 < npos;
            y1 = fminf(y1, p0 ? t0 : 1e30f);
            y2 = fminf(y2, p0 ? 1e30f : t0);
            y1 = fminf(y1, p1 ? t1 : 1e30f);
            y2 = fminf(y2, p1 ? 1e30f : t1);
        }
        float xhi = fminf(y1, GX_HI);
        float xlo = fmaxf(-y2, GX_LO);
        bool ne = (xlo <= xhi);
        #pragma unroll
        for (int q = 0; q < 4; q++) {
            float qlo = (q * 32 + 0.5f) * (1.0f / WW);
            float qhi = (q * 32 + 31.5f) * (1.0f / WW);
            unsigned long long m = __ballot(ne && (xlo <= qhi) && (xhi >= qlo));
            if ((tid & 63) == 0) s_qbits[r][q][(s >= 64) ? 1 : 0] = m;
        }
    }
    __syncthreads();

    // ---- mask output: OR row pairs, store 16B/tile (no compaction) ----
    if (tid < 512) {
        int t = tid >> 1, h = tid & 1;
        int rp = t >> 2, qq = t & 3;
        unsigned long long m = s_qbits[2 * rp][qq][h] | s_qbits[2 * rp + 1][qq][h];
        g_mask[((size_t)frame * 256 + t) * 2 + h] = m;
    }

    // ---- copy out coefficients ----
    {
        float4* dstc = (float4*)(g_coef + (size_t)frame * (NN * COEF_STRIDE));
        const float4* srcc = (const float4*)&s_coef[0][0];
        for (int i = tid; i < (NN * COEF_STRIDE) / 4; i += STPB) dstc[i] = srcc[i];
    }
}

struct F3 { float x, y, z; };

__global__ __launch_bounds__(RTPB) void raster_kernel(
    const float* __restrict__ g_coef,
    const unsigned long long* __restrict__ g_mask,
    int total_tiles,
    float* __restrict__ out)
{
    const int lane = threadIdx.x & 63;
    const int wv   = __builtin_amdgcn_readfirstlane(threadIdx.x >> 6);
    const int wid  = blockIdx.x * (RTPB / 64) + wv;   // 0..8191, wave-uniform
    const int nw   = RBLKS * (RTPB / 64);             // 8192 waves

    const int lx = lane & 31, ly = lane >> 5;
    const f2 lo2 = {-100.f, -100.f};

    // static persistent schedule: exactly ceil(total/nw)=6 tiles per wave,
    // interleaved across frames/regions. No atomics, no sibling-wave wait.
    for (int t = wid; t < total_tiles; t += nw) {
        const int frame = t >> 8;
        const int tile  = t & 255;
        const int rp    = tile >> 2;            // row pair
        const int q     = tile & 3;             // x quarter

        // 128-bit survivor mask, forced to SGPRs
        const unsigned long long* mp = g_mask + ((size_t)t) * 2;
        unsigned long long m0v = mp[0], m1v = mp[1];
        unsigned lo0 = (unsigned)__builtin_amdgcn_readfirstlane((int)(unsigned)m0v);
        unsigned hi0 = (unsigned)__builtin_amdgcn_readfirstlane((int)(unsigned)(m0v >> 32));
        unsigned lo1 = (unsigned)__builtin_amdgcn_readfirstlane((int)(unsigned)m1v);
        unsigned hi1 = (unsigned)__builtin_amdgcn_readfirstlane((int)(unsigned)(m1v >> 32));
        unsigned long long m0 = ((unsigned long long)hi0 << 32) | lo0;
        unsigned long long m1 = ((unsigned long long)hi1 << 32) | lo1;

        const int px  = q * 32 + lx;
        const int row = rp * 2 + ly;
        const float gy = (row + 0.5f) * (1.0f / HH);
        const float gx = (px  + 0.5f) * (1.0f / WW);
        const f2 gy2 = {gy, gy};
        const f2 gx2 = {gx, gx};

        const float* cfr = g_coef + (size_t)frame * (NN * COEF_STRIDE);

        float Tt = 1.f, rr = 0.f, gg = 0.f, bb = 0.f;
        bool live = true;

        // two scalar-mask loops: slots 0-63 (m0), 64-127 (m1); bit index
        // ascending = slot ascending = front-to-back z order.
        #pragma unroll
        for (int half = 0; half < 2; half++) {
            unsigned long long m = half ? m1 : m0;
            const int base = half << 6;
            while (m != 0ull && live) {
                int slot = base + __builtin_ctzll(m);   // uniform -> SALU ff1
                m &= m - 1ull;
                const float* cf = cfr + slot * COEF_STRIDE; // uniform -> s_loads
                const f2* A2 = (const f2*)(cf);
                const f2* B2 = (const f2*)(cf + 12);
                const f2* C2 = (const f2*)(cf + 24);

                f2 qv = {1.f, 1.f};
                #pragma unroll
                for (int j = 0; j < 6; j++) {
                    f2 u = __builtin_elementwise_fma(B2[j], gx2,
                             __builtin_elementwise_fma(A2[j], gy2, C2[j]));
                    u = __builtin_elementwise_max(u, lo2);   // exp2 underflow guard
                    f2 e;
                    e.x = __builtin_amdgcn_exp2f(u.x);
                    e.y = __builtin_amdgcn_exp2f(u.y);
                    qv = __builtin_elementwise_fma(qv, e, qv); // q *= 1 + 2^u
                }
                float cov = __builtin_amdgcn_rcpf(qv.x * qv.y);

                float a = cov * cf[36];
                float w = a * Tt;
                rr = fmaf(w, cf[37], rr);
                gg = fmaf(w, cf[38], gg);
                bb = fmaf(w, cf[39], bb);
                Tt = fmaf(-a, Tt, Tt);

                live = __any(Tt > 2e-3f);   // residual <= T < 2e-3
            }
        }

        size_t o = ((size_t)frame * (HH * WW) + (size_t)row * WW + px) * 3;
        *(F3*)(out + o) = F3{rr, gg, bb};    // coalesced dwordx3 per row segment
    }
}

extern "C" void kernel_launch(void* const* d_in, const int* in_sizes, int n_in,
                              void* d_out, int out_size, void* d_ws, size_t ws_size,
                              hipStream_t stream) {
    const float* traj   = (const float*)d_in[0];
    const float* colors = (const float*)d_in[1];
    const float* alpha  = (const float*)d_in[2];
    const float* zval   = (const float*)d_in[3];
    const void*  csg    = d_in[4];
    float* out = (float*)d_out;

    const int T = in_sizes[0] / STATE_SZ; // 192

    size_t coef_sz = (size_t)T * NN * COEF_STRIDE * sizeof(float); // 3.93 MB
    float* g_coef = (float*)d_ws;
    unsigned long long* g_mask =
        (unsigned long long*)((char*)d_ws + coef_sz);              // 0.79 MB

    setup_kernel<<<T, STPB, 0, stream>>>(traj, colors, alpha, zval, csg,
                                         g_coef, g_mask);
    raster_kernel<<<RBLKS, RTPB, 0, stream>>>(g_coef, g_mask, T * 256, out);
}

// Round 9
// 225.289 us; speedup vs baseline: 1.2274x; 1.2274x over previous
//
#include <hip/hip_runtime.h>

// Soft differentiable rasterizer, forward only. Two-kernel structure.
// R17 -> R18 post-mortem: static persistent schedule had stride 8192 ≡ 0
// mod 256 -> each wave got the SAME tile position across 6 frames
// (temporally correlated = identical workload): no variance reduction,
// retired waves left CUs idle (occupancy 27%, raster 201us). Lesson: the
// HW dispatcher IS a dynamic work queue at block granularity — don't
// replace it, REDUCE ITS GRANULE.
// R18 = R15 proven body + 2-WAVE BLOCKS (128 thr), 24576 blocks, one tile
// per wave, HW-dispatched. Block's two waves take vertically ADJACENT
// tiles (same x-quarter, adjacent row pairs = one 32x4 region): max
// workload correlation -> E[max(w1,w2)]-E[w] trapping cost minimized.
// Cycle model (R15/R17): slot-iter = 68cy main-VALU + 96cy trans; serial
// in-wave = 164cy (matches 160 measured). Floor 96cy/iter (~78us) needs
// cross-wave VALU/trans overlap -> more independently-progressing waves.
// Design (R8/R9/R15): 32x2 px tiles, per-edge line-form interval cull,
// pos-first packing, 128-bit survivor mask per tile, scalar-mask ff1
// next-slot, packed-fp32 sigmoid product (max-guard REQUIRED: prevents
// qv=inf * e=0 NaN when one edge deep-outside and another deep-inside),
// front-to-back T, exit T<2e-3.

#define HH 128
#define WW 128
#define NN 128
#define KK 12
#define STPB 1024
#define RTPB 128                    // 2 waves/block
#define STATE_SZ (NN * KK * 2 + NN) // 3200
#define CULL_U 15.0f
#define COEF_STRIDE 40              // floats per slot: A[12] B[12] C[12] gc[4]
#define PQ_STRIDE 18                // float2 per slot (padded; 36 words)

typedef float f2 __attribute__((ext_vector_type(2)));

__global__ __launch_bounds__(STPB) void setup_kernel(
    const float* __restrict__ traj,
    const float* __restrict__ colors,
    const float* __restrict__ alpha,
    const float* __restrict__ zval,
    const void*  __restrict__ csg_raw,
    float* __restrict__ g_coef,               // [T][128][40]
    unsigned long long* __restrict__ g_mask)  // [T][256][2] 128-bit keep mask
{
    __shared__ __align__(16) float s_coef[NN][COEF_STRIDE];       // 20.5 KB
    __shared__ __align__(16) float2 s_pq[NN][PQ_STRIDE];          // 18 KB
    __shared__ float s_state[STATE_SZ];                           // 12.8 KB
    __shared__ float s_orient[NN];
    __shared__ float s_z[NN];
    __shared__ int   s_slot2prim[NN];
    __shared__ int   s_npos[NN], s_nneg[NN];
    __shared__ unsigned long long s_qbits[HH][4][2];              // 8 KB
    __shared__ int s_mode;

    const int frame = blockIdx.x;
    const int tid   = threadIdx.x;
    const float* st = traj + (size_t)frame * STATE_SZ;

    // ---- stage + csg layout detect (one-wave ballot) + counter init ----
    for (int i = tid; i < STATE_SZ; i += STPB) s_state[i] = st[i];
    if (tid < NN) { s_z[tid] = zval[tid]; s_npos[tid] = 0; s_nneg[tid] = 0; }
    if (tid < 64) {
        unsigned w = (tid < 32) ? ((const unsigned*)csg_raw)[tid] : 0u;
        unsigned long long anyw = __ballot(w > 1u);            // some word not 0/1
        unsigned long long anyb = __ballot((w & 0xFEFEFEFEu) != 0u); // some byte > 1
        if (tid == 0) s_mode = (anyw == 0ull) ? 0 : ((anyb == 0ull) ? 1 : 2);
    }
    __syncthreads();

    // ---- per-prim: orient, g = alpha*sigmoid(alive), z-rank -> slot ----
    if (tid < NN) {
        const int n = tid;
        float area2 = 0.f;
        #pragma unroll
        for (int k = 0; k < KK; k++) {
            int k1 = (k + 1) % KK;
            float v0x = s_state[(n * KK + k)  * 2 + 0];
            float v0y = s_state[(n * KK + k)  * 2 + 1];
            float v1x = s_state[(n * KK + k1) * 2 + 0];
            float v1y = s_state[(n * KK + k1) * 2 + 1];
            area2 += v0x * v1y - v1x * v0y;
        }
        float orient = (area2 > 0.f) ? 1.f : ((area2 < 0.f) ? -1.f : 0.f);
        s_orient[n] = orient;

        float alive = s_state[NN * KK * 2 + n];
        float g = alpha[n] / (1.f + __expf(-alive));

        float zn = s_z[n];
        int rank = 0;
        #pragma unroll 8
        for (int j = 0; j < NN; j++) {
            float zj = s_z[j];
            rank += (zj < zn || (zj == zn && j < n)) ? 1 : 0;
        }
        int slot = (NN - 1) - rank; // slot 0 = frontmost (largest z)
        s_slot2prim[slot] = n;

        int mode = s_mode;
        int sub;
        if (mode == 0)      sub = ((const int*)csg_raw)[n] != 0;
        else if (mode == 1) sub = ((const unsigned char*)csg_raw)[n] != 0;
        else                sub = ((const float*)csg_raw)[n] != 0.f;
        float cs = sub ? 0.f : 1.f;
        s_coef[slot][36] = g;
        s_coef[slot][37] = colors[n * 3 + 0] * cs;
        s_coef[slot][38] = colors[n * 3 + 1] * cs;
        s_coef[slot][39] = colors[n * 3 + 2] * cs;
    }
    __syncthreads();

    // ---- edge coefficients (slot-ordered SoA) ----
    const float QSCALE = 100.0f * 1.4426950408889634f;
    for (int idx = tid; idx < NN * KK; idx += STPB) {
        int slot = idx / KK;
        int k    = idx - slot * KK;
        int n    = s_slot2prim[slot];
        int k1   = (k + 1) % KK;
        float v0x = s_state[(n * KK + k)  * 2 + 0];
        float v0y = s_state[(n * KK + k)  * 2 + 1];
        float v1x = s_state[(n * KK + k1) * 2 + 0];
        float v1y = s_state[(n * KK + k1) * 2 + 1];
        float ex = v1x - v0x, ey = v1y - v0y;
        float q  = -s_orient[n] * QSCALE;
        s_coef[slot][0  + k] = q * ex;                      // A
        s_coef[slot][12 + k] = -q * ey;                     // B
        s_coef[slot][24 + k] = -q * (ex * v0y - ey * v0x);  // C
    }
    __syncthreads();

    // ---- line form per edge: x-constraint t(gy) = Q*gy + P ----
    // B>0: x <= t (+SLACK); B<0: x >= t (stored negated: -x <= -t, +SLACK);
    // B==0: no x-constraint -> neg-bucket entry with t' = +1e30 (never binds).
    // Pos edges packed first (k < npos). STRIDED LOOP (R8 bug: bare if).
    const float SLACK = 0.01f;
    for (int idx = tid; idx < NN * KK; idx += STPB) {
        int slot = idx / KK;
        int k    = idx - slot * KK;
        (void)k;
        float A = s_coef[slot][idx - slot * KK];
        float B = s_coef[slot][12 + (idx - slot * KK)];
        float C = s_coef[slot][24 + (idx - slot * KK)];
        float rcpB = __builtin_amdgcn_rcpf(B);
        float Praw = (CULL_U - C) * rcpB;
        float Qraw = -A * rcpB;
        if (B > 0.f) {
            int i = atomicAdd(&s_npos[slot], 1);
            s_pq[slot][i] = make_float2(Qraw, Praw + SLACK);
        } else if (B < 0.f) {
            int i = atomicAdd(&s_nneg[slot], 1);
            s_pq[slot][(KK - 1) - i] = make_float2(-Qraw, -Praw + SLACK);
        } else { // B == 0: x-independent edge; conservatively no constraint
            int i = atomicAdd(&s_nneg[slot], 1);
            s_pq[slot][(KK - 1) - i] = make_float2(0.f, 1e30f);
        }
    }
    __syncthreads();

    // ---- joint interval cull; 4 x-quarter keep masks per row ----
    // wave covers one row (r const) x 64 slots (s = s0 + lane).
    const float GX_LO = 0.5f / WW;
    const float GX_HI = (WW - 0.5f) / WW;
    for (int j = 0; j < (HH * NN) / STPB; j++) {     // 16 iters
        int idx = j * STPB + tid;
        int r = idx >> 7, s = idx & (NN - 1);
        float gyr = (r + 0.5f) * (1.0f / HH);
        int npos = s_npos[s];
        const float4* pq4 = (const float4*)&s_pq[s][0];
        float y1 = 1e30f, y2 = 1e30f;
        #pragma unroll
        for (int h = 0; h < KK / 2; h++) {
            float4 v = pq4[h];                       // {Q,P,Q,P}
            int k0 = 2 * h, k1 = 2 * h + 1;
            float t0 = fmaf(v.x, gyr, v.y);
            float t1 = fmaf(v.z, gyr, v.w);
            bool p0 = k0 < npos, p1 = k1 < npos;
            y1 = fminf(y1, p0 ? t0 : 1e30f);
            y2 = fminf(y2, p0 ? 1e30f : t0);
            y1 = fminf(y1, p1 ? t1 : 1e30f);
            y2 = fminf(y2, p1 ? 1e30f : t1);
        }
        float xhi = fminf(y1, GX_HI);
        float xlo = fmaxf(-y2, GX_LO);
        bool ne = (xlo <= xhi);
        #pragma unroll
        for (int q = 0; q < 4; q++) {
            float qlo = (q * 32 + 0.5f) * (1.0f / WW);
            float qhi = (q * 32 + 31.5f) * (1.0f / WW);
            unsigned long long m = __ballot(ne && (xlo <= qhi) && (xhi >= qlo));
            if ((tid & 63) == 0) s_qbits[r][q][(s >= 64) ? 1 : 0] = m;
        }
    }
    __syncthreads();

    // ---- mask output: OR row pairs, store 16B/tile (no compaction) ----
    if (tid < 512) {
        int t = tid >> 1, h = tid & 1;
        int rp = t >> 2, qq = t & 3;
        unsigned long long m = s_qbits[2 * rp][qq][h] | s_qbits[2 * rp + 1][qq][h];
        g_mask[((size_t)frame * 256 + t) * 2 + h] = m;
    }

    // ---- copy out coefficients ----
    {
        float4* dstc = (float4*)(g_coef + (size_t)frame * (NN * COEF_STRIDE));
        const float4* srcc = (const float4*)&s_coef[0][0];
        for (int i = tid; i < (NN * COEF_STRIDE) / 4; i += STPB) dstc[i] = srcc[i];
    }
}

struct F3 { float x, y, z; };

__global__ __launch_bounds__(RTPB) void raster_kernel(
    const float* __restrict__ g_coef,
    const unsigned long long* __restrict__ g_mask,
    float* __restrict__ out)
{
    const int tid  = threadIdx.x;
    const int wv   = __builtin_amdgcn_readfirstlane(tid >> 6); // 0 or 1
    const int lane = tid & 63;

    // block = one 32x4 region (frame, row-quad, x-quarter); its two waves
    // take the two ADJACENT row-pair tiles (max workload correlation ->
    // min trapping). b: [frame(192)][rq(32)][q(4)]
    const int b     = blockIdx.x;
    const int frame = b >> 7;
    const int lcl   = b & 127;
    const int q     = lcl & 3;              // x quarter
    const int rp    = (lcl >> 2) * 2 + wv;  // row pair 0..63
    const int tile  = rp * 4 + q;           // 0..255
    const int tgl   = frame * 256 + tile;

    // 128-bit survivor mask, forced to SGPRs
    const unsigned long long* mp = g_mask + (size_t)tgl * 2;
    unsigned long long m0v = mp[0], m1v = mp[1];
    unsigned lo0 = (unsigned)__builtin_amdgcn_readfirstlane((int)(unsigned)m0v);
    unsigned hi0 = (unsigned)__builtin_amdgcn_readfirstlane((int)(unsigned)(m0v >> 32));
    unsigned lo1 = (unsigned)__builtin_amdgcn_readfirstlane((int)(unsigned)m1v);
    unsigned hi1 = (unsigned)__builtin_amdgcn_readfirstlane((int)(unsigned)(m1v >> 32));
    unsigned long long m0 = ((unsigned long long)hi0 << 32) | lo0;
    unsigned long long m1 = ((unsigned long long)hi1 << 32) | lo1;

    const int lx  = lane & 31, ly = lane >> 5;
    const int px  = q * 32 + lx;
    const int row = rp * 2 + ly;
    const float gy = (row + 0.5f) * (1.0f / HH);
    const float gx = (px  + 0.5f) * (1.0f / WW);
    const f2 gy2 = {gy, gy};
    const f2 gx2 = {gx, gx};
    const f2 lo2 = {-100.f, -100.f};

    const float* cfr = g_coef + (size_t)frame * (NN * COEF_STRIDE);

    float Tt = 1.f, rr = 0.f, gg = 0.f, bb = 0.f;
    bool live = true;

    // two scalar-mask loops: slots 0-63 (m0), 64-127 (m1); bit index
    // ascending = slot ascending = front-to-back z order.
    #pragma unroll
    for (int half = 0; half < 2; half++) {
        unsigned long long m = half ? m1 : m0;
        const int base = half << 6;
        while (m != 0ull && live) {
            int slot = base + __builtin_ctzll(m);   // uniform -> SALU ff1
            m &= m - 1ull;
            const float* cf = cfr + slot * COEF_STRIDE; // uniform -> s_loads
            const f2* A2 = (const f2*)(cf);
            const f2* B2 = (const f2*)(cf + 12);
            const f2* C2 = (const f2*)(cf + 24);

            f2 qv = {1.f, 1.f};
            #pragma unroll
            for (int j = 0; j < 6; j++) {
                f2 u = __builtin_elementwise_fma(B2[j], gx2,
                         __builtin_elementwise_fma(A2[j], gy2, C2[j]));
                u = __builtin_elementwise_max(u, lo2);   // REQUIRED: stops qv=inf*e=0 NaN
                f2 e;
                e.x = __builtin_amdgcn_exp2f(u.x);
                e.y = __builtin_amdgcn_exp2f(u.y);
                qv = __builtin_elementwise_fma(qv, e, qv); // q *= 1 + 2^u
            }
            float cov = __builtin_amdgcn_rcpf(qv.x * qv.y);

            float a = cov * cf[36];
            float w = a * Tt;
            rr = fmaf(w, cf[37], rr);
            gg = fmaf(w, cf[38], gg);
            bb = fmaf(w, cf[39], bb);
            Tt = fmaf(-a, Tt, Tt);

            live = __any(Tt > 2e-3f);   // residual <= T < 2e-3
        }
    }

    size_t o = ((size_t)frame * (HH * WW) + (size_t)row * WW + px) * 3;
    *(F3*)(out + o) = F3{rr, gg, bb};    // coalesced dwordx3 per row segment
}

extern "C" void kernel_launch(void* const* d_in, const int* in_sizes, int n_in,
                              void* d_out, int out_size, void* d_ws, size_t ws_size,
                              hipStream_t stream) {
    const float* traj   = (const float*)d_in[0];
    const float* colors = (const float*)d_in[1];
    const float* alpha  = (const float*)d_in[2];
    const float* zval   = (const float*)d_in[3];
    const void*  csg    = d_in[4];
    float* out = (float*)d_out;

    const int T = in_sizes[0] / STATE_SZ; // 192

    size_t coef_sz = (size_t)T * NN * COEF_STRIDE * sizeof(float); // 3.93 MB
    float* g_coef = (float*)d_ws;
    unsigned long long* g_mask =
        (unsigned long long*)((char*)d_ws + coef_sz);              // 0.79 MB

    setup_kernel<<<T, STPB, 0, stream>>>(traj, colors, alpha, zval, csg,
                                         g_coef, g_mask);
    raster_kernel<<<T * 128, RTPB, 0, stream>>>(g_coef, g_mask, out);
}

// Round 10
// 195.839 us; speedup vs baseline: 1.4119x; 1.1504x over previous
//
#include <hip/hip_runtime.h>

// Soft differentiable rasterizer, forward only. Two-kernel structure.
// R18 -> R19: REVERT to R15 (best verified: raster 125us, E2E 196.9us)
// + pk-packed epilogue. Five scheduling attempts (R12/R13/R14/R17/R18)
// all failed to beat R15; issue-cycle model (12 exp2 + 1 rcp @ 8cy
// quarter-rate = 104cy trans + ~56cy VALU = 160cy/slot-iter) puts R15
// within ~6% of the ISSUE-PORT roofline at ~25 effective survivors/tile.
// Occupancy counter reads ~45% across all structures (formula-skewed on
// gfx950) — not a lever signal. Remaining safe cut: epilogue 6 scalar ops
// -> 2 scalar + 2 v_pk_fma_f32 ({rr,gg}, {bb,Tt} f2 accumulators; pk f32
// is full-rate dual-pipe on CDNA4 = 2 FLOP at scalar issue cost),
// saving ~4/160 cy per iteration.
// Design (R8/R9/R15): 32x2 px tiles, per-edge line-form interval cull,
// pos-first packing, 128-bit survivor mask per tile, scalar-mask ff1
// next-slot, packed-fp32 sigmoid product (max-guard REQUIRED: stops
// qv=inf * e=0 NaN), front-to-back T, exit T<2e-3.

#define HH 128
#define WW 128
#define NN 128
#define KK 12
#define STPB 1024
#define RTPB 256
#define STATE_SZ (NN * KK * 2 + NN) // 3200
#define CULL_U 15.0f
#define COEF_STRIDE 40              // floats per slot: A[12] B[12] C[12] gc[4]
#define PQ_STRIDE 18                // float2 per slot (padded; 36 words)

typedef float f2 __attribute__((ext_vector_type(2)));

__global__ __launch_bounds__(STPB) void setup_kernel(
    const float* __restrict__ traj,
    const float* __restrict__ colors,
    const float* __restrict__ alpha,
    const float* __restrict__ zval,
    const void*  __restrict__ csg_raw,
    float* __restrict__ g_coef,               // [T][128][40]
    unsigned long long* __restrict__ g_mask)  // [T][256][2] 128-bit keep mask
{
    __shared__ __align__(16) float s_coef[NN][COEF_STRIDE];       // 20.5 KB
    __shared__ __align__(16) float2 s_pq[NN][PQ_STRIDE];          // 18 KB
    __shared__ float s_state[STATE_SZ];                           // 12.8 KB
    __shared__ float s_orient[NN];
    __shared__ float s_z[NN];
    __shared__ int   s_slot2prim[NN];
    __shared__ int   s_npos[NN], s_nneg[NN];
    __shared__ unsigned long long s_qbits[HH][4][2];              // 8 KB
    __shared__ int s_mode;

    const int frame = blockIdx.x;
    const int tid   = threadIdx.x;
    const float* st = traj + (size_t)frame * STATE_SZ;

    // ---- stage + csg layout detect (one-wave ballot) + counter init ----
    for (int i = tid; i < STATE_SZ; i += STPB) s_state[i] = st[i];
    if (tid < NN) { s_z[tid] = zval[tid]; s_npos[tid] = 0; s_nneg[tid] = 0; }
    if (tid < 64) {
        unsigned w = (tid < 32) ? ((const unsigned*)csg_raw)[tid] : 0u;
        unsigned long long anyw = __ballot(w > 1u);            // some word not 0/1
        unsigned long long anyb = __ballot((w & 0xFEFEFEFEu) != 0u); // some byte > 1
        if (tid == 0) s_mode = (anyw == 0ull) ? 0 : ((anyb == 0ull) ? 1 : 2);
    }
    __syncthreads();

    // ---- per-prim: orient, g = alpha*sigmoid(alive), z-rank -> slot ----
    if (tid < NN) {
        const int n = tid;
        float area2 = 0.f;
        #pragma unroll
        for (int k = 0; k < KK; k++) {
            int k1 = (k + 1) % KK;
            float v0x = s_state[(n * KK + k)  * 2 + 0];
            float v0y = s_state[(n * KK + k)  * 2 + 1];
            float v1x = s_state[(n * KK + k1) * 2 + 0];
            float v1y = s_state[(n * KK + k1) * 2 + 1];
            area2 += v0x * v1y - v1x * v0y;
        }
        float orient = (area2 > 0.f) ? 1.f : ((area2 < 0.f) ? -1.f : 0.f);
        s_orient[n] = orient;

        float alive = s_state[NN * KK * 2 + n];
        float g = alpha[n] / (1.f + __expf(-alive));

        float zn = s_z[n];
        int rank = 0;
        #pragma unroll 8
        for (int j = 0; j < NN; j++) {
            float zj = s_z[j];
            rank += (zj < zn || (zj == zn && j < n)) ? 1 : 0;
        }
        int slot = (NN - 1) - rank; // slot 0 = frontmost (largest z)
        s_slot2prim[slot] = n;

        int mode = s_mode;
        int sub;
        if (mode == 0)      sub = ((const int*)csg_raw)[n] != 0;
        else if (mode == 1) sub = ((const unsigned char*)csg_raw)[n] != 0;
        else                sub = ((const float*)csg_raw)[n] != 0.f;
        float cs = sub ? 0.f : 1.f;
        s_coef[slot][36] = g;
        s_coef[slot][37] = colors[n * 3 + 0] * cs;
        s_coef[slot][38] = colors[n * 3 + 1] * cs;
        s_coef[slot][39] = colors[n * 3 + 2] * cs;
    }
    __syncthreads();

    // ---- edge coefficients (slot-ordered SoA) ----
    const float QSCALE = 100.0f * 1.4426950408889634f;
    for (int idx = tid; idx < NN * KK; idx += STPB) {
        int slot = idx / KK;
        int k    = idx - slot * KK;
        int n    = s_slot2prim[slot];
        int k1   = (k + 1) % KK;
        float v0x = s_state[(n * KK + k)  * 2 + 0];
        float v0y = s_state[(n * KK + k)  * 2 + 1];
        float v1x = s_state[(n * KK + k1) * 2 + 0];
        float v1y = s_state[(n * KK + k1) * 2 + 1];
        float ex = v1x - v0x, ey = v1y - v0y;
        float q  = -s_orient[n] * QSCALE;
        s_coef[slot][0  + k] = q * ex;                      // A
        s_coef[slot][12 + k] = -q * ey;                     // B
        s_coef[slot][24 + k] = -q * (ex * v0y - ey * v0x);  // C
    }
    __syncthreads();

    // ---- line form per edge: x-constraint t(gy) = Q*gy + P ----
    // B>0: x <= t (+SLACK); B<0: x >= t (stored negated: -x <= -t, +SLACK);
    // B==0: no x-constraint -> neg-bucket entry with t' = +1e30 (never binds).
    // Pos edges packed first (k < npos). STRIDED LOOP (R8 bug: bare if).
    const float SLACK = 0.01f;
    for (int idx = tid; idx < NN * KK; idx += STPB) {
        int slot = idx / KK;
        int k    = idx - slot * KK;
        (void)k;
        float A = s_coef[slot][idx - slot * KK];
        float B = s_coef[slot][12 + (idx - slot * KK)];
        float C = s_coef[slot][24 + (idx - slot * KK)];
        float rcpB = __builtin_amdgcn_rcpf(B);
        float Praw = (CULL_U - C) * rcpB;
        float Qraw = -A * rcpB;
        if (B > 0.f) {
            int i = atomicAdd(&s_npos[slot], 1);
            s_pq[slot][i] = make_float2(Qraw, Praw + SLACK);
        } else if (B < 0.f) {
            int i = atomicAdd(&s_nneg[slot], 1);
            s_pq[slot][(KK - 1) - i] = make_float2(-Qraw, -Praw + SLACK);
        } else { // B == 0: x-independent edge; conservatively no constraint
            int i = atomicAdd(&s_nneg[slot], 1);
            s_pq[slot][(KK - 1) - i] = make_float2(0.f, 1e30f);
        }
    }
    __syncthreads();

    // ---- joint interval cull; 4 x-quarter keep masks per row ----
    // wave covers one row (r const) x 64 slots (s = s0 + lane).
    const float GX_LO = 0.5f / WW;
    const float GX_HI = (WW - 0.5f) / WW;
    for (int j = 0; j < (HH * NN) / STPB; j++) {     // 16 iters
        int idx = j * STPB + tid;
        int r = idx >> 7, s = idx & (NN - 1);
        float gyr = (r + 0.5f) * (1.0f / HH);
        int npos = s_npos[s];
        const float4* pq4 = (const float4*)&s_pq[s][0];
        float y1 = 1e30f, y2 = 1e30f;
        #pragma unroll
        for (int h = 0; h < KK / 2; h++) {
            float4 v = pq4[h];                       // {Q,P,Q,P}
            int k0 = 2 * h, k1 = 2 * h + 1;
            float t0 = fmaf(v.x, gyr, v.y);
            float t1 = fmaf(v.z, gyr, v.w);
            bool p0 = k0 < npos, p1 = k1 < npos;
            y1 = fminf(y1, p0 ? t0 : 1e30f);
            y2 = fminf(y2, p0 ? 1e30f : t0);
            y1 = fminf(y1, p1 ? t1 : 1e30f);
            y2 = fminf(y2, p1 ? 1e30f : t1);
        }
        float xhi = fminf(y1, GX_HI);
        float xlo = fmaxf(-y2, GX_LO);
        bool ne = (xlo <= xhi);
        #pragma unroll
        for (int q = 0; q < 4; q++) {
            float qlo = (q * 32 + 0.5f) * (1.0f / WW);
            float qhi = (q * 32 + 31.5f) * (1.0f / WW);
            unsigned long long m = __ballot(ne && (xlo <= qhi) && (xhi >= qlo));
            if ((tid & 63) == 0) s_qbits[r][q][(s >= 64) ? 1 : 0] = m;
        }
    }
    __syncthreads();

    // ---- mask output: OR row pairs, store 16B/tile (no compaction) ----
    if (tid < 512) {
        int t = tid >> 1, h = tid & 1;
        int rp = t >> 2, qq = t & 3;
        unsigned long long m = s_qbits[2 * rp][qq][h] | s_qbits[2 * rp + 1][qq][h];
        g_mask[((size_t)frame * 256 + t) * 2 + h] = m;
    }

    // ---- copy out coefficients ----
    {
        float4* dstc = (float4*)(g_coef + (size_t)frame * (NN * COEF_STRIDE));
        const float4* srcc = (const float4*)&s_coef[0][0];
        for (int i = tid; i < (NN * COEF_STRIDE) / 4; i += STPB) dstc[i] = srcc[i];
    }
}

struct F3 { float x, y, z; };

__global__ __launch_bounds__(RTPB) void raster_kernel(
    const float* __restrict__ g_coef,
    const unsigned long long* __restrict__ g_mask,
    float* __restrict__ out)
{
    const int tid   = threadIdx.x;
    const int wv    = __builtin_amdgcn_readfirstlane(tid >> 6);
    const int lane  = tid & 63;
    const int frame = blockIdx.y;
    const int tile  = blockIdx.x * 4 + wv;  // 0..255 (4 waves = 4 x-quarters
    const int rp    = tile >> 2;            //  of ONE row pair: max corr.)
    const int q     = tile & 3;             // x quarter

    // 128-bit survivor mask, forced to SGPRs (readfirstlane per 32b half)
    const unsigned long long* mp = g_mask + ((size_t)frame * 256 + tile) * 2;
    unsigned long long m0v = mp[0], m1v = mp[1];
    unsigned lo0 = (unsigned)__builtin_amdgcn_readfirstlane((int)(unsigned)m0v);
    unsigned hi0 = (unsigned)__builtin_amdgcn_readfirstlane((int)(unsigned)(m0v >> 32));
    unsigned lo1 = (unsigned)__builtin_amdgcn_readfirstlane((int)(unsigned)m1v);
    unsigned hi1 = (unsigned)__builtin_amdgcn_readfirstlane((int)(unsigned)(m1v >> 32));
    unsigned long long m0 = ((unsigned long long)hi0 << 32) | lo0;
    unsigned long long m1 = ((unsigned long long)hi1 << 32) | lo1;

    const int lx  = lane & 31, ly = lane >> 5;
    const int px  = q * 32 + lx;
    const int row = rp * 2 + ly;
    const float gy = (row + 0.5f) * (1.0f / HH);
    const float gx = (px  + 0.5f) * (1.0f / WW);
    const f2 gy2 = {gy, gy};
    const f2 gx2 = {gx, gx};
    const f2 lo2 = {-100.f, -100.f};

    const float* cfr = g_coef + (size_t)frame * (NN * COEF_STRIDE);

    f2 rg = {0.f, 0.f};      // {rr, gg} packed accumulator
    f2 bt = {0.f, 1.f};      // {bb, Tt} packed accumulator
    bool live = true;

    // two scalar-mask loops: slots 0-63 (m0), 64-127 (m1); bit index
    // ascending = slot ascending = front-to-back z order.
    #pragma unroll
    for (int half = 0; half < 2; half++) {
        unsigned long long m = half ? m1 : m0;
        const int base = half << 6;
        while (m != 0ull && live) {
            int slot = base + __builtin_ctzll(m);   // uniform -> SALU ff1
            m &= m - 1ull;
            const float* cf = cfr + slot * COEF_STRIDE; // uniform -> s_loads
            const f2* A2 = (const f2*)(cf);
            const f2* B2 = (const f2*)(cf + 12);
            const f2* C2 = (const f2*)(cf + 24);

            f2 qv = {1.f, 1.f};
            #pragma unroll
            for (int j = 0; j < 6; j++) {
                f2 u = __builtin_elementwise_fma(B2[j], gx2,
                         __builtin_elementwise_fma(A2[j], gy2, C2[j]));
                u = __builtin_elementwise_max(u, lo2);   // stops qv=inf*e=0 NaN
                f2 e;
                e.x = __builtin_amdgcn_exp2f(u.x);
                e.y = __builtin_amdgcn_exp2f(u.y);
                qv = __builtin_elementwise_fma(qv, e, qv); // q *= 1 + 2^u
            }
            float cov = __builtin_amdgcn_rcpf(qv.x * qv.y);

            // pk-packed compositing epilogue (2 scalar + 2 v_pk_fma_f32)
            float Tt = bt.y;
            float a = cov * cf[36];
            float w = a * Tt;
            f2 ww; ww.x = w; ww.y = w;
            f2 cg; cg.x = cf[37]; cg.y = cf[38];
            rg = __builtin_elementwise_fma(ww, cg, rg);      // {rr,gg} += w*{cr,cg}
            f2 wa; wa.x = w; wa.y = -a;                      // neg folds to pk modifier
            f2 ct; ct.x = cf[39]; ct.y = Tt;
            bt = __builtin_elementwise_fma(wa, ct, bt);      // {bb+=w*cb, Tt+=-a*Tt}

            live = __any(bt.y > 2e-3f);   // residual <= T < 2e-3
        }
    }

    size_t o = ((size_t)frame * (HH * WW) + (size_t)row * WW + px) * 3;
    *(F3*)(out + o) = F3{rg.x, rg.y, bt.x};  // coalesced dwordx3 per row segment
}

extern "C" void kernel_launch(void* const* d_in, const int* in_sizes, int n_in,
                              void* d_out, int out_size, void* d_ws, size_t ws_size,
                              hipStream_t stream) {
    const float* traj   = (const float*)d_in[0];
    const float* colors = (const float*)d_in[1];
    const float* alpha  = (const float*)d_in[2];
    const float* zval   = (const float*)d_in[3];
    const void*  csg    = d_in[4];
    float* out = (float*)d_out;

    const int T = in_sizes[0] / STATE_SZ; // 192

    size_t coef_sz = (size_t)T * NN * COEF_STRIDE * sizeof(float); // 3.93 MB
    float* g_coef = (float*)d_ws;
    unsigned long long* g_mask =
        (unsigned long long*)((char*)d_ws + coef_sz);              // 0.79 MB

    setup_kernel<<<T, STPB, 0, stream>>>(traj, colors, alpha, zval, csg,
                                         g_coef, g_mask);
    dim3 grid(256 / 4, T); // 64 x 192, wave = one 32x2 tile
    raster_kernel<<<grid, RTPB, 0, stream>>>(g_coef, g_mask, out);
}